// Round 7
// baseline (142.371 us; speedup 1.0000x reference)
//
#include <hip/hip_runtime.h>

// ---------------- types & helpers ----------------
typedef __attribute__((ext_vector_type(8))) short short8;   // 8 bf16 (4 VGPRs)
typedef __attribute__((ext_vector_type(4))) float f32x4;

#define LEAKY_F 0.3f

typedef __attribute__((address_space(3))) void lds_t;
typedef __attribute__((address_space(1))) void gmem_t;
#define G2L(g, l) __builtin_amdgcn_global_load_lds((const gmem_t*)(g), (lds_t*)(l), 16, 0, 0)

__device__ __forceinline__ unsigned short f2bf(float f) {
    union { float f; unsigned u; } v; v.f = f;
    unsigned u = v.u;
    return (unsigned short)((u + 0x7fffu + ((u >> 16) & 1u)) >> 16);  // RNE
}
__device__ __forceinline__ float bf2f(unsigned short u) {
    union { unsigned u; float f; } v; v.u = ((unsigned)u) << 16; return v.f;
}

// ---------------- cast x f32 -> bf16 into padded [32][1028][512] ----------------
__global__ void cast_pad_x(const float* __restrict__ in, unsigned short* __restrict__ out) {
    int i = blockIdx.x * 256 + threadIdx.x;     // 8 elems per thread
    long g = (long)i * 8;
    int row = (int)(g >> 9);                    // 0..32767 (b*1024+t)
    int b = row >> 10;
    long o = ((long)(row + (b << 2) + 2) << 9) + (g & 511);
    const float4* p = (const float4*)(in + g);
    float4 a = p[0], c = p[1];
    union { unsigned short s[8]; uint4 v; } u;
    u.s[0] = f2bf(a.x); u.s[1] = f2bf(a.y); u.s[2] = f2bf(a.z); u.s[3] = f2bf(a.w);
    u.s[4] = f2bf(c.x); u.s[5] = f2bf(c.y); u.s[6] = f2bf(c.z); u.s[7] = f2bf(c.w);
    *(uint4*)(out + o) = u.v;
}

// ---------------- zero halo rows {0,1,1026,1027} of padded buffer ----------------
__global__ void zero_pads(unsigned short* __restrict__ p, int cin) {
    int j = blockIdx.x * 256 + threadIdx.x;     // one uint4 (8 elems) per thread
    int upb = cin >> 1;                          // units per batch (4 rows * cin / 8)
    int b = j / upb, rem = j % upb;
    int upr = cin >> 3;                          // units per row
    int r4 = rem / upr;
    int col = (rem % upr) * 8;
    int rowp = (r4 < 2) ? r4 : (r4 + 1024);
    *(uint4*)(p + ((long)b * 1028 + rowp) * cin + col) = make_uint4(0u, 0u, 0u, 0u);
}

// ---------------- weight rearrange: [CH][CIN][5] -> [CH][5*CIN] bf16 ----------------
__global__ void prep_w(const float* __restrict__ w, unsigned short* __restrict__ out, int CIN, int n) {
    int i = blockIdx.x * 256 + threadIdx.x;
    if (i >= n) return;
    int ch = i / (CIN * 5);
    int rem = i % (CIN * 5);
    int tap = rem / CIN;
    int cin = rem % CIN;
    out[ch * (5 * CIN) + tap * CIN + cin] = f2bf(w[(ch * CIN + cin) * 5 + tap]);
}

// ---------------- conv-as-GEMM + fused epilogue ----------------
// A padded [32][1028][CIN] bf16; im2col linear. Tile 64x256, BK=32,
// 256 threads = 4 waves 1Mx4N (wave 64x64, acc 4x4). Ring-of-3 LDS (64 KB
// total -> 2 blocks/CU at grid 512), counted vmcnt(5), ONE barrier/step.
// Inter-block overlap hides the per-step stalls (m97/m114 mechanism).
template<int CIN, bool PRED>
__global__ __launch_bounds__(256, 2) void gemm_conv_fused(
    const unsigned short* __restrict__ A,
    const unsigned short* __restrict__ W,    // [256][5*CIN]
    const float* __restrict__ bias,
    const float* __restrict__ gam,
    const float* __restrict__ bet,
    const float* __restrict__ wlin,
    const float* __restrict__ blin,
    const unsigned char* __restrict__ mask,
    unsigned short* __restrict__ Yln,        // [32][1028][256] padded
    float* __restrict__ Ypred)               // [32768]
{
    constexpr int KW = 5 * CIN;
    constexpr int S  = KW / 32;
    constexpr int ASLOT = 64 * 32;           // 2048 elems (4 KB)
    constexpr int BSLOT = 256 * 32;          // 8192 elems (16 KB)
    __shared__ __align__(16) unsigned short smem[3 * (ASLOT + BSLOT)];  // 60 KB
    __shared__ float pb[1024];                                          // 4 KB

    const int tid = threadIdx.x, lane = tid & 63, wn = tid >> 6;  // 4 waves, wm=0
    const int blk = blockIdx.x;                 // 0..511
    const int bb = blk >> 4, tl0 = (blk & 15) << 6;
    const long rowbase = (long)bb * 1028 + tl0;

    // staging: A 1 call/thread, B 4 calls/thread. LDS dest linear; global
    // source 16B-seg pre-swizzled with sg = q ^ (r&3) (4 segs per 32-k row).
    long asrc; int adst;
    {
        int r = tid >> 2, q = tid & 3, sg = q ^ (r & 3);
        asrc = (rowbase + r) * (long)CIN + sg * 8;
        adst = tid * 8;
    }
    long bsrc[4]; int bdst[4];
    #pragma unroll
    for (int c = 0; c < 4; c++) {
        int u = c * 256 + tid;
        int r = u >> 2, q = u & 3, sg = q ^ (r & 3);
        bsrc[c] = (long)r * KW + sg * 8;
        bdst[c] = u * 8;
    }

    auto stage = [&](int t, int slot) {
        const int k0 = t * 32;
        G2L(A + asrc + k0, &smem[slot * ASLOT + adst]);
        unsigned short* b = smem + 3 * ASLOT + slot * BSLOT;
        #pragma unroll
        for (int c = 0; c < 4; c++) G2L(W + bsrc[c] + k0, b + bdst[c]);
    };

    const int l15 = lane & 15, lhi = (lane >> 4) & 3;
    const int sgoff = ((lhi ^ (l15 & 3)) & 3) << 3;
    const int brow0 = wn * 64;

    f32x4 acc[4][4] = {};

    // prologue: tiles 0,1 in flight (5 loads each per wave)
    stage(0, 0);
    stage(1, 1);

    int rb = 0;
    #pragma unroll 1
    for (int t = 0; t < S; ++t) {
        if (t < S - 1) { asm volatile("s_waitcnt vmcnt(5)" ::: "memory"); }
        else           { asm volatile("s_waitcnt vmcnt(0)" ::: "memory"); }
        __builtin_amdgcn_sched_barrier(0);
        __builtin_amdgcn_s_barrier();
        __builtin_amdgcn_sched_barrier(0);

        const unsigned short* ab = smem + rb * ASLOT;
        const unsigned short* bp = smem + 3 * ASLOT + rb * BSLOT;
        short8 af[4], bg[4];
        #pragma unroll
        for (int m = 0; m < 4; m++)
            af[m] = *(const short8*)&ab[(m * 16 + l15) * 32 + sgoff];
        #pragma unroll
        for (int n = 0; n < 4; n++)
            bg[n] = *(const short8*)&bp[(brow0 + n * 16 + l15) * 32 + sgoff];

        if (t + 2 < S) stage(t + 2, (rb == 0) ? 2 : (rb - 1));

        asm volatile("s_waitcnt lgkmcnt(0)" ::: "memory");
        __builtin_amdgcn_sched_barrier(0);
        __builtin_amdgcn_s_setprio(1);
        #pragma unroll
        for (int m = 0; m < 4; m++)
            #pragma unroll
            for (int n = 0; n < 4; n++)
                acc[m][n] = __builtin_amdgcn_mfma_f32_16x16x32_bf16(af[m], bg[n], acc[m][n], 0, 0, 0);
        __builtin_amdgcn_s_setprio(0);
        __builtin_amdgcn_sched_barrier(0);

        rb = (rb == 2) ? 0 : (rb + 1);
    }

    // ================= fused epilogue =================
    __syncthreads();   // all reads done; safe to reuse smem

    pb[tid]       = bias[tid];
    pb[256 + tid] = gam[tid];
    pb[512 + tid] = bet[tid];
    pb[768 + tid] = PRED ? wlin[tid] : 0.f;
    __syncthreads();

    // acc -> LDS tile [64][256] bf16 (bias+leaky), 16B-unit XOR swizzle
    unsigned short* tile = smem;
    #pragma unroll
    for (int n = 0; n < 4; n++) {
        const int col = wn * 64 + n * 16 + l15;
        const float bv = pb[col];
        const int u0 = col >> 3, ce = col & 7;
        #pragma unroll
        for (int m = 0; m < 4; m++) {
            const int rA = m * 16 + lhi * 4;
            #pragma unroll
            for (int q = 0; q < 4; q++) {
                const int row = rA + q;
                float v = acc[m][n][q] + bv;
                v = v > 0.f ? v : LEAKY_F * v;
                tile[row * 256 + ((u0 ^ (row & 7)) << 3) + ce] = f2bf(v);
            }
        }
    }
    __syncthreads();

    // per-row reduce (4 lanes/row, 64 rows) & output
    const int rid = tid >> 2, jq = tid & 3;
    const int r7 = rid & 7;
    float vals[8][8];
    float s1 = 0.f, s2 = 0.f, sgw = 0.f, sgc = 0.f, sbw = 0.f;
    #pragma unroll
    for (int u4 = 0; u4 < 8; u4++) {
        const int u = u4 * 4 + jq;
        short8 pk = *(const short8*)&tile[rid * 256 + ((u ^ r7) << 3)];
        #pragma unroll
        for (int e = 0; e < 8; e++) {
            float v = bf2f((unsigned short)pk[e]);
            vals[u4][e] = v;
            s1 += v; s2 += v * v;
        }
        if (PRED) {
            const int c0 = u * 8;
            f32x4 ga = *(const f32x4*)&pb[256 + c0], gb = *(const f32x4*)&pb[260 + c0];
            f32x4 wa = *(const f32x4*)&pb[768 + c0], wb = *(const f32x4*)&pb[772 + c0];
            f32x4 ba = *(const f32x4*)&pb[512 + c0], bb2 = *(const f32x4*)&pb[516 + c0];
            #pragma unroll
            for (int e = 0; e < 4; e++) {
                sgw += vals[u4][e] * ga[e] * wa[e] + vals[u4][e + 4] * gb[e] * wb[e];
                sgc += ga[e] * wa[e] + gb[e] * wb[e];
                sbw += ba[e] * wa[e] + bb2[e] * wb[e];
            }
        }
    }
    s1 += __shfl_xor(s1, 1); s1 += __shfl_xor(s1, 2);
    s2 += __shfl_xor(s2, 1); s2 += __shfl_xor(s2, 2);
    const float mean = s1 * (1.f / 256.f);
    const float var  = s2 * (1.f / 256.f) - mean * mean;
    const float rs   = rsqrtf(var + 1e-5f);
    const long grow  = (long)blk * 64 + rid;

    if (PRED) {
        sgw += __shfl_xor(sgw, 1); sgw += __shfl_xor(sgw, 2);
        sgc += __shfl_xor(sgc, 1); sgc += __shfl_xor(sgc, 2);
        sbw += __shfl_xor(sbw, 1); sbw += __shfl_xor(sbw, 2);
        if (jq == 0) {
            float p = rs * (sgw - mean * sgc) + sbw + blin[0];
            if (mask[grow]) p = 0.f;
            Ypred[grow] = p;
        }
    } else {
        const int bnum = (int)(grow >> 10);
        const long prow = grow + (bnum << 2) + 2;
        #pragma unroll
        for (int u4 = 0; u4 < 8; u4++) {
            const int u = u4 * 4 + jq;
            const int c0 = u * 8;
            f32x4 ga = *(const f32x4*)&pb[256 + c0], gb = *(const f32x4*)&pb[260 + c0];
            f32x4 ba = *(const f32x4*)&pb[512 + c0], bb2 = *(const f32x4*)&pb[516 + c0];
            union { unsigned short s[8]; uint4 v; } o;
            #pragma unroll
            for (int e = 0; e < 4; e++) {
                o.s[e]     = f2bf((vals[u4][e]     - mean) * rs * ga[e] + ba[e]);
                o.s[e + 4] = f2bf((vals[u4][e + 4] - mean) * rs * gb[e] + bb2[e]);
            }
            *(uint4*)(Yln + prow * 256 + c0) = o.v;
        }
    }
}

// ---------------- averaged-over-durations (exact reference algorithm) ----------------
__global__ void avg_kernel(const float* __restrict__ target, const int* __restrict__ dr,
                           float* __restrict__ outAvg) {
    __shared__ float vcum[4097];
    __shared__ float ncum[4097];
    __shared__ float sS[256];
    __shared__ float sC[256];
    __shared__ int   sI[256];
    int b = blockIdx.x, tid = threadIdx.x;
    const float* tb = target + b * 4096;
    float lv[16]; float ls = 0.f, lc = 0.f;
    #pragma unroll
    for (int j = 0; j < 16; j++) {
        float v = tb[tid * 16 + j]; lv[j] = v; ls += v; lc += (v != 0.f) ? 1.f : 0.f;
    }
    sS[tid] = ls; sC[tid] = lc;
    __syncthreads();
    for (int off = 1; off < 256; off <<= 1) {
        float a = 0.f, c2 = 0.f;
        if (tid >= off) { a = sS[tid - off]; c2 = sC[tid - off]; }
        __syncthreads();
        sS[tid] += a; sC[tid] += c2;
        __syncthreads();
    }
    float pS = tid ? sS[tid - 1] : 0.f, pC = tid ? sC[tid - 1] : 0.f;
    if (tid == 0) { vcum[0] = 0.f; ncum[0] = 0.f; }
    float run = pS, runc = pC;
    #pragma unroll
    for (int j = 0; j < 16; j++) {
        run += lv[j]; runc += (lv[j] != 0.f) ? 1.f : 0.f;
        vcum[tid * 16 + j + 1] = run; ncum[tid * 16 + j + 1] = runc;
    }
    const int* db = dr + b * 1024;
    int ld[4]; int lsum = 0;
    #pragma unroll
    for (int j = 0; j < 4; j++) { ld[j] = db[tid * 4 + j]; lsum += ld[j]; }
    sI[tid] = lsum;
    __syncthreads();
    for (int off = 1; off < 256; off <<= 1) {
        int a = 0; if (tid >= off) a = sI[tid - off];
        __syncthreads();
        sI[tid] += a;
        __syncthreads();
    }
    int run2 = tid ? sI[tid - 1] : 0;
    #pragma unroll
    for (int j = 0; j < 4; j++) {
        run2 += ld[j];
        int e = run2, s0 = e - ld[j];
        float sums = vcum[e] - vcum[s0];
        float cnt  = ncum[e] - ncum[s0];
        outAvg[b * 1024 + tid * 4 + j] = (cnt == 0.f) ? 0.f : sums / cnt;
    }
}

// ---------------- energy_emb: 1->256 conv, K=3, pad 1 ----------------
__global__ void emb_kernel(const float* __restrict__ avg, const float* __restrict__ wemb,
                           const float* __restrict__ bemb, float* __restrict__ out) {
    int id = blockIdx.x * 256 + threadIdx.x;
    int t4 = id & 255;
    int ch = (id >> 8) & 255;
    int b  = id >> 16;
    int t0 = t4 * 4;
    const float* a = avg + b * 1024;
    float am1 = (t0 - 1 >= 0) ? a[t0 - 1] : 0.f;
    float a0 = a[t0], a1 = a[t0 + 1], a2 = a[t0 + 2], a3 = a[t0 + 3];
    float a4 = (t0 + 4 < 1024) ? a[t0 + 4] : 0.f;
    float w0 = wemb[ch * 3], w1 = wemb[ch * 3 + 1], w2 = wemb[ch * 3 + 2], bb = bemb[ch];
    float4 o;
    o.x = bb + am1 * w0 + a0 * w1 + a1 * w2;
    o.y = bb + a0 * w0 + a1 * w1 + a2 * w2;
    o.z = bb + a1 * w0 + a2 * w1 + a3 * w2;
    o.w = bb + a2 * w0 + a3 * w1 + a4 * w2;
    *(float4*)(out + (((b << 8) | ch) << 10) + t0) = o;
}

// ---------------- launcher ----------------
extern "C" void kernel_launch(void* const* d_in, const int* in_sizes, int n_in,
                              void* d_out, int out_size, void* d_ws, size_t ws_size,
                              hipStream_t stream) {
    const float* x      = (const float*)d_in[0];
    const float* target = (const float*)d_in[1];
    const int*   dr     = (const int*)d_in[2];
    const unsigned char* mask = (const unsigned char*)d_in[3];
    const float* w1   = (const float*)d_in[4];
    const float* b1   = (const float*)d_in[5];
    const float* g1   = (const float*)d_in[6];
    const float* be1  = (const float*)d_in[7];
    const float* w2   = (const float*)d_in[8];
    const float* b2   = (const float*)d_in[9];
    const float* g2   = (const float*)d_in[10];
    const float* be2  = (const float*)d_in[11];
    const float* wlin = (const float*)d_in[12];
    const float* blin = (const float*)d_in[13];
    const float* wemb = (const float*)d_in[14];
    const float* bemb = (const float*)d_in[15];

    char* ws = (char*)d_ws;
    unsigned short* xbp  = (unsigned short*)ws;                    // 33,685,504 B  [32][1028][512]
    unsigned short* h1bp = (unsigned short*)(ws + 33685504);       // 16,842,752 B  [32][1028][256]
    unsigned short* wr1  = (unsigned short*)(ws + 50528256);       //  1,310,720 B
    unsigned short* wr2  = (unsigned short*)(ws + 51838976);       //    655,360 B

    float* outPred = (float*)d_out;            // 32768
    float* outAvg  = outPred + 32768;          // 32768
    float* outEmb  = outPred + 65536;          // 8,388,608

    // 1. cast+pad x; zero halos of both padded buffers
    cast_pad_x<<<8192, 256, 0, stream>>>(x, xbp);
    zero_pads<<<32, 256, 0, stream>>>(xbp, 512);
    zero_pads<<<16, 256, 0, stream>>>(h1bp, 256);
    // 2. weight prep
    prep_w<<<2560, 256, 0, stream>>>(w1, wr1, 512, 256 * 512 * 5);
    prep_w<<<1280, 256, 0, stream>>>(w2, wr2, 256, 256 * 256 * 5);
    // 3. conv1 + bias + leaky + LN1 -> padded bf16
    gemm_conv_fused<512, false><<<512, 256, 0, stream>>>(
        xbp, wr1, b1, g1, be1, wlin, blin, mask, h1bp, outPred);
    // 4. conv2 + bias + leaky + LN2 + linear + mask -> energy_pred
    gemm_conv_fused<256, true><<<512, 256, 0, stream>>>(
        h1bp, wr2, b2, g2, be2, wlin, blin, mask, h1bp, outPred);
    // 5. averaged target -> output 1
    avg_kernel<<<32, 256, 0, stream>>>(target, dr, outAvg);
    // 6. emb conv -> output 2
    emb_kernel<<<8192, 256, 0, stream>>>(outAvg, wemb, bemb, outEmb);
}